// Round 8
// baseline (284.811 us; speedup 1.0000x reference)
//
#include <hip/hip_runtime.h>
#include <hip/hip_bf16.h>
#include <math.h>

// Problem constants
#define HH 80
#define WW 80
#define NPIX 6400          // H*W
#define CC 36              // 6 labels x 6 channels
#define CCP 48             // padded: label l at dwords l*8.. ; c==6 is ones->norm
#define NC 6
#define NUM_ITER 5
#define JS 20              // j-slices
#define SLICE (NPIX / JS)  // 320
#define JTILES (SLICE / 32)// 10
#define IBLK 50            // i-blocks: 4 waves x 2 i-tiles x 16 = 128 i per block
#define SHARD 4            // k_update threads per (n,l)

typedef __attribute__((ext_vector_type(8))) short bfrag;   // 8 bf16 (4 VGPR)
typedef __attribute__((ext_vector_type(4))) float f32x4;
typedef __attribute__((ext_vector_type(2))) float f32x2;

// coords prescaled so bilateral w = exp2(-(dy^2+dx^2+d0^2+d1^2+d2^2))
// spatial  w = exp2(-RS*(dy^2+dx^2)), RS = 128/18
__device__ __constant__ const float kSA = 0.08838834764831845f;  // sqrt(1/(128*ln2))
__device__ __constant__ const float kSB = 5.663898078577187f;    // sqrt(1/(0.045*ln2))
__device__ __constant__ const float kRS = 7.11111111f;           // 128/18

__device__ inline unsigned short f2bf(float f) {
    unsigned u = __builtin_bit_cast(unsigned, f);
    unsigned r = (u + 0x7FFFu + ((u >> 16) & 1u)) >> 16;
    return (unsigned short)r;
}

// ---------------------------------------------------------------------------
// init: pf SoA prescaled (y,x,f0,f1,f2); sm0 = softmax(unary) in fp32 [N][36]
// and bf16-transposed smbT [48][N] with rows l*8+6 = 1.0, l*8+7 = 0.
// Also zeroes out[6] (d_out is poisoned before every call).
// ---------------------------------------------------------------------------
__global__ __launch_bounds__(256) void k_init(const float* __restrict__ unary,
                                              const float* __restrict__ feat,
                                              float* __restrict__ sm,
                                              unsigned short* __restrict__ smbT,
                                              float* __restrict__ pf,
                                              float* __restrict__ out) {
    int i = blockIdx.x * 256 + threadIdx.x;
    if (blockIdx.x == 0 && threadIdx.x < NC) out[threadIdx.x] = 0.f;
    if (i >= NPIX) return;
    int y = i / WW, x = i - y * WW;
    pf[0 * NPIX + i] = kSA * (float)y;
    pf[1 * NPIX + i] = kSA * (float)x;
    pf[2 * NPIX + i] = kSB * feat[i * 3 + 0];
    pf[3 * NPIX + i] = kSB * feat[i * 3 + 1];
    pf[4 * NPIX + i] = kSB * feat[i * 3 + 2];
    float v[NC], mx = -1e30f;
#pragma unroll
    for (int c = 0; c < NC; c++) { v[c] = unary[i * NC + c]; mx = fmaxf(mx, v[c]); }
    float sum = 0.f;
#pragma unroll
    for (int c = 0; c < NC; c++) { v[c] = __expf(v[c] - mx); sum += v[c]; }
    float inv = 1.f / sum;
#pragma unroll
    for (int l = 0; l < NC; l++) {
#pragma unroll
        for (int c = 0; c < NC; c++) {
            float s = v[c] * inv;
            sm[(size_t)i * CC + l * NC + c] = s;
            smbT[(size_t)(l * 8 + c) * NPIX + i] = f2bf(s);
        }
        smbT[(size_t)(l * 8 + 6) * NPIX + i] = 0x3F80;  // ones -> normalizer
        smbT[(size_t)(l * 8 + 7) * NPIX + i] = 0;
    }
}

// ---------------------------------------------------------------------------
// N^2 MFMA pass, both kernels, 2 i-tiles per wave, j-slice staged in LDS.
// Block: 4 waves; wave owns i-tiles [it0, it0+32). Grid = IBLK x JS = 1000.
// smbT tile staged with XOR swizzle (byte ^= (row&7)<<4, 16B slots) so the
// 16-rows-same-col ds_read_b128 pattern is bank-conflict-free (m201 pattern).
// A layout: row = lane&15, k = 8*(lane>>4)+e ; B: col = lane&15, same k;
// D: col = lane&15, row = 4*(lane>>4)+reg   (verified rounds 4-7)
// Output: ONE packed array: dword = (bf16(spat)<<16) | bf16(bil)
// ---------------------------------------------------------------------------
__global__ __launch_bounds__(256) void k_bil(const unsigned short* __restrict__ smbT,
                                             const float* __restrict__ pf,
                                             unsigned* __restrict__ part) {
    __shared__ __align__(16) float s_pf[5 * SLICE];            // 6.4 KB
    __shared__ __align__(16) unsigned short s_smT[48 * SLICE]; // 30.7 KB, swizzled
    int tid = threadIdx.x, bid = blockIdx.x;
    int s = bid / IBLK, ib = bid - s * IBLK;
    int j00 = s * SLICE;

    // stage pf (5 x 320 floats, coalesced)
    for (int idx = tid; idx < 5 * SLICE; idx += 256) {
        int a = idx / SLICE, jl = idx - a * SLICE;
        s_pf[idx] = pf[(size_t)a * NPIX + j00 + jl];
    }
    // stage smbT (48 rows x 40 16B-slots, coalesced global, swizzled LDS)
    for (int slot = tid; slot < 48 * (SLICE / 8); slot += 256) {
        int row = slot / (SLICE / 8), c16 = slot - row * (SLICE / 8);
        uint4 v = *(const uint4*)(smbT + (size_t)row * NPIX + j00 + c16 * 8);
        unsigned off = (unsigned)(row * (SLICE * 2) + c16 * 16) ^ ((unsigned)(row & 7) << 4);
        *(uint4*)((char*)s_smT + off) = v;
    }
    __syncthreads();

    int wv = tid >> 6, lane = tid & 63, r = lane & 15, gq = lane >> 4;
    int it0 = (ib * 4 + wv) * 32;
    int iA = it0 + r, iB = iA + 16;

    float yA = pf[iA], xA = pf[NPIX + iA];
    float fA0 = pf[2 * NPIX + iA], fA1 = pf[3 * NPIX + iA], fA2 = pf[4 * NPIX + iA];
    float yB = pf[iB], xB = pf[NPIX + iB];
    float fB0 = pf[2 * NPIX + iB], fB1 = pf[3 * NPIX + iB], fB2 = pf[4 * NPIX + iB];
    const f32x2 rs2 = {kRS, kRS};

    f32x4 abA[3], asA[3], abB[3], asB[3];
#pragma unroll
    for (int t = 0; t < 3; t++) {
        abA[t] = (f32x4){0.f, 0.f, 0.f, 0.f};
        asA[t] = (f32x4){0.f, 0.f, 0.f, 0.f};
        abB[t] = (f32x4){0.f, 0.f, 0.f, 0.f};
        asB[t] = (f32x4){0.f, 0.f, 0.f, 0.f};
    }

    for (int jt = 0; jt < JTILES; jt++) {
        int jl = jt * 32 + 8 * gq;          // this lane's k-base within slice
        const float* pl = s_pf + jl;
        f32x4 yj0 = *(const f32x4*)(pl);
        f32x4 yj1 = *(const f32x4*)(pl + 4);
        f32x4 xj0 = *(const f32x4*)(pl + SLICE);
        f32x4 xj1 = *(const f32x4*)(pl + SLICE + 4);
        f32x4 c00 = *(const f32x4*)(pl + 2 * SLICE);
        f32x4 c01 = *(const f32x4*)(pl + 2 * SLICE + 4);
        f32x4 c10 = *(const f32x4*)(pl + 3 * SLICE);
        f32x4 c11 = *(const f32x4*)(pl + 3 * SLICE + 4);
        f32x4 c20 = *(const f32x4*)(pl + 4 * SLICE);
        f32x4 c21 = *(const f32x4*)(pl + 4 * SLICE + 4);
        bfrag Bf[3];
#pragma unroll
        for (int t = 0; t < 3; t++) {
            unsigned off = (unsigned)((16 * t + r) * (SLICE * 2) + jl * 2)
                           ^ ((unsigned)(r & 7) << 4);
            Bf[t] = *(const bfrag*)((const char*)s_smT + off);
        }

        union { unsigned u[4]; bfrag v; } Ab, As, Bb, Bs;
#pragma unroll
        for (int p = 0; p < 4; p++) {
            f32x4 ysrc = (p < 2) ? yj0 : yj1;
            f32x4 xsrc = (p < 2) ? xj0 : xj1;
            f32x4 s0 = (p < 2) ? c00 : c01;
            f32x4 s1 = (p < 2) ? c10 : c11;
            f32x4 s2 = (p < 2) ? c20 : c21;
            int e = (p & 1) * 2;
            f32x2 yj = {ysrc[e], ysrc[e + 1]};
            f32x2 xj = {xsrc[e], xsrc[e + 1]};
            f32x2 u0 = {s0[e], s0[e + 1]};
            f32x2 u1 = {s1[e], s1[e + 1]};
            f32x2 u2 = {s2[e], s2[e + 1]};

            // i-tile A
            f32x2 dy = (f32x2){yA, yA} - yj;
            f32x2 dx = (f32x2){xA, xA} - xj;
            f32x2 sp = dy * dy; sp = dx * dx + sp;
            f32x2 d0 = (f32x2){fA0, fA0} - u0;
            f32x2 d1 = (f32x2){fA1, fA1} - u1;
            f32x2 d2 = (f32x2){fA2, fA2} - u2;
            f32x2 a = d0 * d0 + sp; a = d1 * d1 + a; a = d2 * d2 + a;
            f32x2 aspt = rs2 * sp;
            float wb0 = __builtin_amdgcn_exp2f(-a[0]);
            float wb1 = __builtin_amdgcn_exp2f(-a[1]);
            float ws0 = __builtin_amdgcn_exp2f(-aspt[0]);
            float ws1 = __builtin_amdgcn_exp2f(-aspt[1]);
            asm("v_cvt_pk_bf16_f32 %0, %1, %2" : "=v"(Ab.u[p]) : "v"(wb0), "v"(wb1));
            asm("v_cvt_pk_bf16_f32 %0, %1, %2" : "=v"(As.u[p]) : "v"(ws0), "v"(ws1));

            // i-tile B
            dy = (f32x2){yB, yB} - yj;
            dx = (f32x2){xB, xB} - xj;
            sp = dy * dy; sp = dx * dx + sp;
            d0 = (f32x2){fB0, fB0} - u0;
            d1 = (f32x2){fB1, fB1} - u1;
            d2 = (f32x2){fB2, fB2} - u2;
            a = d0 * d0 + sp; a = d1 * d1 + a; a = d2 * d2 + a;
            aspt = rs2 * sp;
            wb0 = __builtin_amdgcn_exp2f(-a[0]);
            wb1 = __builtin_amdgcn_exp2f(-a[1]);
            ws0 = __builtin_amdgcn_exp2f(-aspt[0]);
            ws1 = __builtin_amdgcn_exp2f(-aspt[1]);
            asm("v_cvt_pk_bf16_f32 %0, %1, %2" : "=v"(Bb.u[p]) : "v"(wb0), "v"(wb1));
            asm("v_cvt_pk_bf16_f32 %0, %1, %2" : "=v"(Bs.u[p]) : "v"(ws0), "v"(ws1));
        }
#pragma unroll
        for (int t = 0; t < 3; t++) {
            abA[t] = __builtin_amdgcn_mfma_f32_16x16x32_bf16(Ab.v, Bf[t], abA[t], 0, 0, 0);
            asA[t] = __builtin_amdgcn_mfma_f32_16x16x32_bf16(As.v, Bf[t], asA[t], 0, 0, 0);
            abB[t] = __builtin_amdgcn_mfma_f32_16x16x32_bf16(Bb.v, Bf[t], abB[t], 0, 0, 0);
            asB[t] = __builtin_amdgcn_mfma_f32_16x16x32_bf16(Bs.v, Bf[t], asB[t], 0, 0, 0);
        }
    }
#pragma unroll
    for (int t = 0; t < 3; t++)
#pragma unroll
        for (int d = 0; d < 4; d++) {
            int irow = it0 + 4 * gq + d;
            unsigned pkA, pkB;
            asm("v_cvt_pk_bf16_f32 %0, %1, %2" : "=v"(pkA) : "v"(abA[t][d]), "v"(asA[t][d]));
            asm("v_cvt_pk_bf16_f32 %0, %1, %2" : "=v"(pkB) : "v"(abB[t][d]), "v"(asB[t][d]));
            part[((size_t)s * NPIX + irow) * CCP + 16 * t + r] = pkA;
            part[((size_t)s * NPIX + irow + 16) * CCP + 16 * t + r] = pkB;
        }
}

// ---------------------------------------------------------------------------
// update: SHARD threads per (n,l), each reduces JS/SHARD slices of packed part
// (bil = lo bf16, spat = hi bf16; norm = ch l*8+6), shuffle-combine, then
// shard 0 does message, pairwise, q, softmax. LAST: ELBO into out[6].
// Grid = NPIX*NC*SHARD/256 = 600 blocks (exact; no early returns).
// ---------------------------------------------------------------------------
template <bool LAST>
__global__ __launch_bounds__(256) void k_update(const unsigned* __restrict__ part,
                                                const float* __restrict__ unary,
                                                const float* __restrict__ SW,
                                                const float* __restrict__ BW,
                                                const float* __restrict__ CM,
                                                const float* __restrict__ LG,
                                                float* __restrict__ sm,
                                                unsigned short* __restrict__ smbT,
                                                float* __restrict__ out) {
    __shared__ float sSW[36], sBW[36], sCM[36], sLG[36];
    __shared__ float bins[NC];
    int tid = threadIdx.x;
    if (tid < 36) { sSW[tid] = SW[tid]; sBW[tid] = BW[tid]; sCM[tid] = CM[tid]; sLG[tid] = LG[tid]; }
    if (LAST && tid < NC) bins[tid] = 0.f;
    __syncthreads();
    int u = blockIdx.x * 256 + tid;
    int pr = u >> 2, h = u & 3;       // SHARD = 4
    int n = pr / NC, l = pr - n * NC;

    float fb[NC], fs[NC], nb = 0.f, ns = 0.f;
#pragma unroll
    for (int c = 0; c < NC; c++) { fb[c] = 0.f; fs[c] = 0.f; }
#pragma unroll
    for (int s5 = 0; s5 < JS / SHARD; s5++) {
        int s = h * (JS / SHARD) + s5;
        const uint4* pp = (const uint4*)(part + ((size_t)s * NPIX + n) * CCP + l * 8);
        uint4 v0 = pp[0], v1 = pp[1];
        unsigned d[7] = {v0.x, v0.y, v0.z, v0.w, v1.x, v1.y, v1.z};
#pragma unroll
        for (int c = 0; c < NC; c++) {
            fb[c] += __builtin_bit_cast(float, d[c] << 16);
            fs[c] += __builtin_bit_cast(float, d[c] & 0xFFFF0000u);
        }
        nb += __builtin_bit_cast(float, d[6] << 16);
        ns += __builtin_bit_cast(float, d[6] & 0xFFFF0000u);
    }
    // combine the 4 shards (adjacent lanes)
#pragma unroll
    for (int st = 1; st < SHARD; st <<= 1) {
#pragma unroll
        for (int c = 0; c < NC; c++) {
            fb[c] += __shfl_xor(fb[c], st);
            fs[c] += __shfl_xor(fs[c], st);
        }
        nb += __shfl_xor(nb, st);
        ns += __shfl_xor(ns, st);
    }
    float invb = 1.f / nb, invs = 1.f / ns;
#pragma unroll
    for (int c = 0; c < NC; c++) { fb[c] *= invb; fs[c] *= invs; }

    float m[NC];
#pragma unroll
    for (int c = 0; c < NC; c++) {
        float a = 0.f;
#pragma unroll
        for (int cp = 0; cp < NC; cp++)
            a += sSW[c * NC + cp] * fs[cp] + sBW[c * NC + cp] * fb[cp];
        m[c] = a;
    }
    const float* up = unary + (size_t)n * NC;
    if (!LAST) {
        if (h == 0) {
            float qv[NC], mxq = -1e30f;
#pragma unroll
            for (int c = 0; c < NC; c++) {
                float pw = 0.f;
#pragma unroll
                for (int cp = 0; cp < NC; cp++) pw += sCM[c * NC + cp] * m[cp];
                qv[c] = up[c] + sLG[c * NC + l] - pw;
                mxq = fmaxf(mxq, qv[c]);
            }
            float e[NC], ssum = 0.f;
#pragma unroll
            for (int c = 0; c < NC; c++) { e[c] = __expf(qv[c] - mxq); ssum += e[c]; }
            float inv = 1.f / ssum;
            float* sp = sm + (size_t)n * CC + l * NC;
#pragma unroll
            for (int c = 0; c < NC; c++) {
                float sv = e[c] * inv;
                sp[c] = sv;
                smbT[(size_t)(l * 8 + c) * NPIX + n] = f2bf(sv);
            }
        }
    } else {
        if (h == 0) {
            const float* sp = sm + (size_t)n * CC + l * NC;
            float v = 0.f;
#pragma unroll
            for (int c = 0; c < NC; c++) {
                float sv = sp[c];
                v += sv * (up[c] + sLG[c * NC + l] - logf(sv + 1e-10f) - m[c]);
            }
            atomicAdd(&bins[l], v);
        }
        __syncthreads();
        if (tid < NC) atomicAdd(&out[tid], bins[tid]);
    }
}

// ---------------------------------------------------------------------------
extern "C" void kernel_launch(void* const* d_in, const int* in_sizes, int n_in,
                              void* d_out, int out_size, void* d_ws, size_t ws_size,
                              hipStream_t stream) {
    const float* unary = (const float*)d_in[0];  // [N][6]
    const float* feat  = (const float*)d_in[1];  // [N][3]
    const float* CM    = (const float*)d_in[2];  // [6][6]
    const float* LG    = (const float*)d_in[3];
    const float* SW    = (const float*)d_in[4];
    const float* BW    = (const float*)d_in[5];
    float* out = (float*)d_out;

    float* ws = (float*)d_ws;
    float* pf = ws;                                     // 5N
    float* sm = pf + (size_t)5 * NPIX;                  // 36N fp32
    unsigned short* smbT = (unsigned short*)(sm + (size_t)CC * NPIX);  // 48 x N bf16
    unsigned* part = (unsigned*)(ws + (size_t)65 * NPIX);  // JS*N*48 dwords (packed bf16 pair)

    k_init<<<25, 256, 0, stream>>>(unary, feat, sm, smbT, pf, out);

    for (int it = 0; it < NUM_ITER; it++) {
        k_bil<<<IBLK * JS, 256, 0, stream>>>(smbT, pf, part);
        if (it < NUM_ITER - 1)
            k_update<false><<<600, 256, 0, stream>>>(part, unary, SW, BW, CM, LG,
                                                     sm, smbT, out);
        else
            k_update<true><<<600, 256, 0, stream>>>(part, unary, SW, BW, CM, LG,
                                                    sm, smbT, out);
    }
}